// Round 1
// baseline (1471.697 us; speedup 1.0000x reference)
//
#include <hip/hip_runtime.h>
#include <math.h>

#define NBASE 100000
#define DIM   1024
#define NE    8
#define NSUP  128
#define KSEL  15000
#define NB1   4096
#define CAP   256

// ---------- reduction helpers (256-thread blocks) ----------
__device__ __forceinline__ float wave_sum(float v) {
    #pragma unroll
    for (int off = 32; off > 0; off >>= 1) v += __shfl_down(v, off, 64);
    return v;
}

// all threads receive the result; safe for back-to-back reuse of `red`
__device__ __forceinline__ float block_sum(float v, float* red) {
    int lane = threadIdx.x & 63, wv = threadIdx.x >> 6;
    v = wave_sum(v);
    __syncthreads();
    if (lane == 0) red[wv] = v;
    __syncthreads();
    return red[0] + red[1] + red[2] + red[3];
}

// ---------- K1: q_e = normalize(sum of 128 normalized support rows) ----------
__global__ void k1_query(const float* __restrict__ F, float* __restrict__ Q) {
    int e = blockIdx.x, tid = threadIdx.x;
    __shared__ float red[4];
    float ax = 0.f, ay = 0.f, az = 0.f, aw = 0.f;
    for (int r = 0; r < NSUP; ++r) {
        const float4* row = (const float4*)(F + (size_t)(e * 1024 + r) * DIM);
        float4 f = row[tid];
        float ss = f.x * f.x + f.y * f.y + f.z * f.z + f.w * f.w;
        ss = block_sum(ss, red);
        float inv = 1.f / fmaxf(sqrtf(ss), 1e-12f);
        ax += f.x * inv; ay += f.y * inv; az += f.z * inv; aw += f.w * inv;
    }
    float ss = ax * ax + ay * ay + az * az + aw * aw;
    ss = block_sum(ss, red);
    float inv = 1.f / fmaxf(sqrtf(ss), 1e-12f);
    float4* q4 = (float4*)Q;
    q4[e * 256 + tid] = make_float4(ax * inv, ay * inv, az * inv, aw * inv);
}

// ---------- K2: s[i][e] = q_e . B[i] / ||B[i]||, inv_norm[i] ----------
__global__ void k2_sim(const float* __restrict__ Bse, const float* __restrict__ Q,
                       float* __restrict__ S, float* __restrict__ InvN) {
    __shared__ float q_sh[NE * DIM];      // 32 KB
    __shared__ float red[4 * 9];
    __shared__ float tot[9];
    int tid = threadIdx.x;
    int lane = tid & 63, wv = tid >> 6;
    {
        const float4* Q4 = (const float4*)Q;
        float4* q4 = (float4*)q_sh;
        for (int k = tid; k < NE * DIM / 4; k += 256) q4[k] = Q4[k];
    }
    __syncthreads();
    const float4* q4 = (const float4*)q_sh;
    for (int i = blockIdx.x; i < NBASE; i += gridDim.x) {
        float4 b = ((const float4*)(Bse + (size_t)i * DIM))[tid];
        float pv[9];
        pv[8] = b.x * b.x + b.y * b.y + b.z * b.z + b.w * b.w;
        #pragma unroll
        for (int e = 0; e < NE; ++e) {
            float4 q = q4[e * 256 + tid];
            pv[e] = b.x * q.x + b.y * q.y + b.z * q.z + b.w * q.w;
        }
        #pragma unroll
        for (int v = 0; v < 9; ++v) {
            float t = pv[v];
            #pragma unroll
            for (int off = 32; off > 0; off >>= 1) t += __shfl_down(t, off, 64);
            pv[v] = t;
        }
        __syncthreads();   // protect red/tot reuse across rows
        if (lane == 0) {
            #pragma unroll
            for (int v = 0; v < 9; ++v) red[wv * 9 + v] = pv[v];
        }
        __syncthreads();
        if (tid < 9) tot[tid] = red[tid] + red[9 + tid] + red[18 + tid] + red[27 + tid];
        __syncthreads();
        if (tid < 8) {
            float inv = 1.f / fmaxf(sqrtf(tot[8]), 1e-12f);
            S[(size_t)i * NE + tid] = tot[tid] * inv;
            if (tid == 0) InvN[i] = inv;
        }
    }
}

// ---------- K3: exact top-K set per e via two-level histogram; writes Flags ----------
__global__ void k3_select(const float* __restrict__ S, unsigned char* __restrict__ Flags) {
    int e = blockIdx.x, tid = threadIdx.x;
    __shared__ int hist[NB1];             // 16 KB
    __shared__ int shist[256];
    __shared__ int sh_i[5];               // B, G, B2, G2, ncand
    __shared__ float cv[CAP];
    __shared__ int   ci[CAP];

    const float lo = -1.0001f;
    const float w  = 2.0002f / NB1;
    const float invw = NB1 / 2.0002f;

    for (int b = tid; b < NB1; b += 256) hist[b] = 0;
    __syncthreads();
    for (int i = tid; i < NBASE; i += 256) {
        float s = S[(size_t)i * NE + e];
        int b = (int)((s - lo) * invw);
        b = min(max(b, 0), NB1 - 1);
        atomicAdd(&hist[b], 1);
    }
    __syncthreads();
    if (tid == 0) {
        int cum = 0, B = 0;
        for (int b = NB1 - 1; b >= 0; --b) {
            int c = hist[b];
            if (cum + c >= KSEL) { B = b; break; }
            cum += c;
        }
        sh_i[0] = B; sh_i[1] = cum;
    }
    __syncthreads();
    int B = sh_i[0];
    int need1 = KSEL - sh_i[1];
    float lo2 = lo + B * w;
    float invw2 = invw * 256.0f;

    for (int b = tid; b < 256; b += 256) shist[b] = 0;
    __syncthreads();
    for (int i = tid; i < NBASE; i += 256) {
        float s = S[(size_t)i * NE + e];
        int b = (int)((s - lo) * invw);
        b = min(max(b, 0), NB1 - 1);
        if (b == B) {
            int b2 = (int)((s - lo2) * invw2);
            b2 = min(max(b2, 0), 255);
            atomicAdd(&shist[b2], 1);
        }
    }
    __syncthreads();
    if (tid == 0) {
        int cum = 0, B2 = 0;
        for (int b = 255; b >= 0; --b) {
            int c = shist[b];
            if (cum + c >= need1) { B2 = b; break; }
            cum += c;
        }
        sh_i[2] = B2; sh_i[3] = cum; sh_i[4] = 0;
    }
    __syncthreads();
    int B2 = sh_i[2];
    int need2 = need1 - sh_i[3];

    // full flags pass + candidate collection for the boundary sub-bin
    for (int i = tid; i < NBASE; i += 256) {
        float s = S[(size_t)i * NE + e];
        int b = (int)((s - lo) * invw);
        b = min(max(b, 0), NB1 - 1);
        int flag = 0;
        if (b > B) flag = 1;
        else if (b == B) {
            int b2 = (int)((s - lo2) * invw2);
            b2 = min(max(b2, 0), 255);
            if (b2 > B2) flag = 1;
            else if (b2 == B2) {
                int k = atomicAdd(&sh_i[4], 1);
                if (k < CAP) { cv[k] = s; ci[k] = i; }
            }
        }
        Flags[(size_t)i * NE + e] = (unsigned char)flag;
    }
    __syncthreads();
    if (tid == 0) {
        int n = min(sh_i[4], CAP);
        // pick need2 winners: value desc, index asc (matches top_k tie-break)
        for (int t = 0; t < need2 && t < n; ++t) {
            int best = -1;
            for (int j = 0; j < n; ++j) {
                if (ci[j] < 0) continue;
                if (best < 0 || cv[j] > cv[best] ||
                    (cv[j] == cv[best] && ci[j] < ci[best])) best = j;
            }
            if (best < 0) break;
            Flags[(size_t)ci[best] * NE + e] = 1;
            ci[best] = -1;
        }
    }
}

// ---------- K4: Acc[e] += sum over selected rows of sqrt(s)*B[i]/||B[i]|| ----------
__global__ void k4_accum(const float* __restrict__ Bse, const float* __restrict__ S,
                         const float* __restrict__ InvN, const unsigned char* __restrict__ Flags,
                         float* __restrict__ Acc) {
    int tid = threadIdx.x;
    float acc[NE][4];
    #pragma unroll
    for (int e = 0; e < NE; ++e)
        #pragma unroll
        for (int j = 0; j < 4; ++j) acc[e][j] = 0.f;

    for (int i = blockIdx.x; i < NBASE; i += gridDim.x) {
        unsigned long long fl = *(const unsigned long long*)(Flags + (size_t)i * NE);
        if (!fl) continue;
        float inv = InvN[i];
        const float* srow = S + (size_t)i * NE;
        float coef[NE];
        #pragma unroll
        for (int e = 0; e < NE; ++e) {
            coef[e] = ((fl >> (8 * e)) & 0xffull)
                        ? sqrtf(fmaxf(srow[e], 0.f)) * inv : 0.f;
        }
        float4 b = ((const float4*)(Bse + (size_t)i * DIM))[tid];
        #pragma unroll
        for (int e = 0; e < NE; ++e) {
            acc[e][0] += coef[e] * b.x;
            acc[e][1] += coef[e] * b.y;
            acc[e][2] += coef[e] * b.z;
            acc[e][3] += coef[e] * b.w;
        }
    }
    #pragma unroll
    for (int e = 0; e < NE; ++e)
        #pragma unroll
        for (int j = 0; j < 4; ++j)
            atomicAdd(&Acc[e * DIM + tid * 4 + j], acc[e][j]);
}

// ---------- K5: approx_e = normalize(Acc_e) ----------
__global__ void k5_norm(const float* __restrict__ Acc, float* __restrict__ A) {
    int e = blockIdx.x, tid = threadIdx.x;
    __shared__ float red[4];
    float4 a = ((const float4*)Acc)[e * 256 + tid];
    float ss = a.x * a.x + a.y * a.y + a.z * a.z + a.w * a.w;
    ss = block_sum(ss, red);
    float inv = 1.f / fmaxf(sqrtf(ss), 1e-12f);
    ((float4*)A)[e * 256 + tid] = make_float4(a.x * inv, a.y * inv, a.z * inv, a.w * inv);
}

// ---------- K6: out = normalize(fn - (fn.a) * a), fn = normalize(F row) ----------
__global__ void k6_out(const float* __restrict__ F, const float* __restrict__ A,
                       float* __restrict__ Out) {
    int rid = blockIdx.x, tid = threadIdx.x;
    int e = rid >> 10;
    __shared__ float red[4];
    float4 f = ((const float4*)F)[(size_t)rid * 256 + tid];
    float4 a = ((const float4*)A)[e * 256 + tid];
    float ss = f.x * f.x + f.y * f.y + f.z * f.z + f.w * f.w;
    ss = block_sum(ss, red);
    float invf = 1.f / fmaxf(sqrtf(ss), 1e-12f);
    f.x *= invf; f.y *= invf; f.z *= invf; f.w *= invf;
    float c = f.x * a.x + f.y * a.y + f.z * a.z + f.w * a.w;
    c = block_sum(c, red);
    float4 r = make_float4(f.x - c * a.x, f.y - c * a.y, f.z - c * a.z, f.w - c * a.w);
    float rs = r.x * r.x + r.y * r.y + r.z * r.z + r.w * r.w;
    rs = block_sum(rs, red);
    float invr = 1.f / fmaxf(sqrtf(rs), 1e-12f);
    ((float4*)Out)[(size_t)rid * 256 + tid] =
        make_float4(r.x * invr, r.y * invr, r.z * invr, r.w * invr);
}

extern "C" void kernel_launch(void* const* d_in, const int* in_sizes, int n_in,
                              void* d_out, int out_size, void* d_ws, size_t ws_size,
                              hipStream_t stream) {
    const float* F   = (const float*)d_in[0];   // (8,1024,1024)
    const float* Bse = (const float*)d_in[1];   // (100000,1024)
    // d_in[2] support_labels: only its shape (128) matters
    float* Out = (float*)d_out;

    char* ws = (char*)d_ws;
    size_t off = 0;
    auto alloc = [&](size_t bytes) -> void* {
        void* p = ws + off;
        off += (bytes + 255) & ~(size_t)255;
        return p;
    };
    float* Q    = (float*)alloc((size_t)NE * DIM * 4);
    float* S    = (float*)alloc((size_t)NBASE * NE * 4);
    float* InvN = (float*)alloc((size_t)NBASE * 4);
    unsigned char* Flags = (unsigned char*)alloc((size_t)NBASE * NE);
    float* Acc  = (float*)alloc((size_t)NE * DIM * 4);
    float* A    = (float*)alloc((size_t)NE * DIM * 4);

    k1_query<<<NE, 256, 0, stream>>>(F, Q);
    k2_sim<<<2048, 256, 0, stream>>>(Bse, Q, S, InvN);
    k3_select<<<NE, 256, 0, stream>>>(S, Flags);
    hipMemsetAsync(Acc, 0, (size_t)NE * DIM * 4, stream);
    k4_accum<<<512, 256, 0, stream>>>(Bse, S, InvN, Flags, Acc);
    k5_norm<<<NE, 256, 0, stream>>>(Acc, A);
    k6_out<<<NE * 1024, 256, 0, stream>>>(F, A, Out);
}

// Round 2
// 880.048 us; speedup vs baseline: 1.6723x; 1.6723x over previous
//
#include <hip/hip_runtime.h>
#include <math.h>

#define NBASE 100000
#define DIM   1024
#define NE    8
#define NSUP  128
#define KSEL  15000
#define NB1   4096
#define CAP2  1024

// ---------- helpers ----------
__device__ __forceinline__ float dot4(float4 a, float4 b) {
    return a.x*b.x + a.y*b.y + a.z*b.z + a.w*b.w;
}
__device__ __forceinline__ float4 scale4(float4 a, float s) {
    return make_float4(a.x*s, a.y*s, a.z*s, a.w*s);
}
__device__ __forceinline__ float4 add4(float4 a, float4 b) {
    return make_float4(a.x+b.x, a.y+b.y, a.z+b.z, a.w+b.w);
}
// butterfly: all lanes end with the full 64-lane sum
__device__ __forceinline__ float wave_sum_xor(float v) {
    #pragma unroll
    for (int m = 1; m < 64; m <<= 1) v += __shfl_xor(v, m, 64);
    return v;
}
__device__ __forceinline__ float wave_sum(float v) {
    #pragma unroll
    for (int off = 32; off > 0; off >>= 1) v += __shfl_down(v, off, 64);
    return v;
}
__device__ __forceinline__ float block_sum(float v, float* red) {
    int lane = threadIdx.x & 63, wv = threadIdx.x >> 6;
    v = wave_sum(v);
    __syncthreads();
    if (lane == 0) red[wv] = v;
    __syncthreads();
    return red[0] + red[1] + red[2] + red[3];
}
// identical binning in every kernel (bit-identical codegen)
__device__ __forceinline__ int bin1(float s) {
    int b = (int)((s + 1.0001f) * ((float)NB1 / 2.0002f));
    return min(max(b, 0), NB1 - 1);
}
__device__ __forceinline__ int bin2(float s, int B) {
    float lo2 = -1.0001f + (float)B * (2.0002f / (float)NB1);
    int b = (int)((s - lo2) * ((float)NB1 / 2.0002f * 256.0f));
    return min(max(b, 0), 255);
}

// ---------- K1a: normalize each support row, partial-sum per (e, group of 4 rows) ----------
// grid 256 = NE*32, one row per wave
__global__ void k1a(const float* __restrict__ F, float* __restrict__ Qpart) {
    int blk = blockIdx.x;
    int e = blk >> 5, g = blk & 31;
    int wv = threadIdx.x >> 6, lane = threadIdx.x & 63;
    int r = g * 4 + wv;
    const float4* row = (const float4*)(F + ((size_t)e * 1024 + r) * DIM);
    float4 f0 = row[lane], f1 = row[64+lane], f2 = row[128+lane], f3 = row[192+lane];
    float ss = dot4(f0,f0) + dot4(f1,f1) + dot4(f2,f2) + dot4(f3,f3);
    ss = wave_sum_xor(ss);
    float inv = 1.f / fmaxf(sqrtf(ss), 1e-12f);
    __shared__ float part[4][1024];
    float4* p4 = (float4*)part[wv];
    p4[lane]     = scale4(f0, inv);
    p4[64+lane]  = scale4(f1, inv);
    p4[128+lane] = scale4(f2, inv);
    p4[192+lane] = scale4(f3, inv);
    __syncthreads();
    int tid = threadIdx.x;
    const float4* pp = (const float4*)part;
    float4 s = add4(add4(pp[tid], pp[256+tid]), add4(pp[512+tid], pp[768+tid]));
    ((float4*)Qpart)[(size_t)(e*32+g)*256 + tid] = s;
}

// ---------- K1b: combine 32 partials per e, normalize -> Q ----------
__global__ void k1b(const float* __restrict__ Qpart, float* __restrict__ Q) {
    int e = blockIdx.x, tid = threadIdx.x;
    __shared__ float red[4];
    const float4* qp = (const float4*)Qpart;
    float4 s = make_float4(0.f,0.f,0.f,0.f);
    #pragma unroll 4
    for (int g = 0; g < 32; ++g) s = add4(s, qp[(size_t)(e*32+g)*256 + tid]);
    float ss = block_sum(dot4(s,s), red);
    float inv = 1.f / fmaxf(sqrtf(ss), 1e-12f);
    ((float4*)Q)[e*256 + tid] = scale4(s, inv);
}

// ---------- K2: wave-per-row sims; writes S[i][e], S_T[e][i], InvN[i] ----------
// grid 25000 blocks, 4 waves = 4 rows per block
__global__ void k2_sim(const float* __restrict__ Bse, const float* __restrict__ Q,
                       float* __restrict__ S, float* __restrict__ ST,
                       float* __restrict__ InvN) {
    __shared__ float q_sh[NE * DIM];   // 32 KB
    int tid = threadIdx.x, wv = tid >> 6, lane = tid & 63;
    {
        const float4* Q4 = (const float4*)Q;
        float4* q4 = (float4*)q_sh;
        #pragma unroll
        for (int k = 0; k < 8; ++k) q4[k*256 + tid] = Q4[k*256 + tid];
    }
    __syncthreads();
    const float4* q4 = (const float4*)q_sh;
    size_t i = (size_t)blockIdx.x * 4 + wv;
    const float4* b4 = (const float4*)(Bse + i * DIM);
    float4 b0 = b4[lane], b1 = b4[64+lane], b2 = b4[128+lane], b3 = b4[192+lane];
    float pv[9];
    pv[8] = dot4(b0,b0) + dot4(b1,b1) + dot4(b2,b2) + dot4(b3,b3);
    #pragma unroll
    for (int e = 0; e < NE; ++e) {
        float4 q0 = q4[e*256+lane],     q1 = q4[e*256+64+lane];
        float4 q2 = q4[e*256+128+lane], q3 = q4[e*256+192+lane];
        pv[e] = dot4(b0,q0) + dot4(b1,q1) + dot4(b2,q2) + dot4(b3,q3);
    }
    #pragma unroll
    for (int v = 0; v < 9; ++v) pv[v] = wave_sum_xor(pv[v]);
    float invn = 1.f / fmaxf(sqrtf(pv[8]), 1e-12f);
    if (lane < 8) {
        float v = pv[0];
        #pragma unroll
        for (int e = 1; e < 8; ++e) v = (lane == e) ? pv[e] : v;
        float sv = v * invn;
        S[i*NE + lane] = sv;
        ST[(size_t)lane*NBASE + i] = sv;
    }
    if (lane == 0) InvN[i] = invn;
}

// ---------- K3a: per-e 4096-bin histogram (parallel, coalesced over S_T) ----------
// grid 256 = NE*32
__global__ void k3a(const float* __restrict__ ST, int* __restrict__ Hist) {
    int e = blockIdx.x >> 5, chunk = blockIdx.x & 31;
    __shared__ int h[NB1];
    for (int b = threadIdx.x; b < NB1; b += 256) h[b] = 0;
    __syncthreads();
    const int per = (NBASE + 31) / 32;
    int i0 = chunk * per, i1 = min(i0 + per, NBASE);
    for (int i = i0 + threadIdx.x; i < i1; i += 256) {
        float s = ST[(size_t)e*NBASE + i];
        atomicAdd(&h[bin1(s)], 1);
    }
    __syncthreads();
    for (int b = threadIdx.x; b < NB1; b += 256)
        if (h[b]) atomicAdd(&Hist[e*NB1 + b], h[b]);
}

// ---------- K3b: find boundary bin B and need1 per e ----------
__global__ void k3b(const int* __restrict__ Hist, int* __restrict__ Meta) {
    int e = blockIdx.x, tid = threadIdx.x;
    __shared__ int gsum[256];
    int s = 0;
    #pragma unroll
    for (int j = 0; j < 16; ++j) s += Hist[e*NB1 + tid*16 + j];
    gsum[tid] = s;
    __syncthreads();
    if (tid == 0) {
        int cum = 0;
        for (int g = 255; g >= 0; --g) {
            if (cum + gsum[g] >= KSEL) {
                for (int b = g*16 + 15;; --b) {
                    int c = Hist[e*NB1 + b];
                    if (cum + c >= KSEL) { Meta[e*4+0] = b; Meta[e*4+1] = KSEL - cum; break; }
                    cum += c;
                }
                break;
            }
            cum += gsum[g];
        }
    }
}

// ---------- K3c: 256-sub-bin histogram of boundary bin ----------
__global__ void k3c(const float* __restrict__ ST, const int* __restrict__ Meta,
                    int* __restrict__ SubHist) {
    int e = blockIdx.x >> 5, chunk = blockIdx.x & 31;
    int B = Meta[e*4];
    __shared__ int h[256];
    h[threadIdx.x] = 0;
    __syncthreads();
    const int per = (NBASE + 31) / 32;
    int i0 = chunk * per, i1 = min(i0 + per, NBASE);
    for (int i = i0 + threadIdx.x; i < i1; i += 256) {
        float s = ST[(size_t)e*NBASE + i];
        if (bin1(s) == B) atomicAdd(&h[bin2(s, B)], 1);
    }
    __syncthreads();
    if (h[threadIdx.x]) atomicAdd(&SubHist[e*256 + threadIdx.x], h[threadIdx.x]);
}

// ---------- K3d: find sub-bin B2 and need2 per e ----------
__global__ void k3d(const int* __restrict__ SubHist, int* __restrict__ Meta) {
    int e = blockIdx.x;
    if (threadIdx.x != 0) return;
    int need1 = Meta[e*4+1], cum = 0;
    for (int b = 255; b >= 0; --b) {
        int c = SubHist[e*256 + b];
        if (cum + c >= need1) { Meta[e*4+2] = b; Meta[e*4+3] = need1 - cum; return; }
        cum += c;
    }
    Meta[e*4+2] = 0; Meta[e*4+3] = need1 - cum;
}

// ---------- K3e: flags pass (1 thread per row, all 8 e) + boundary candidates ----------
__global__ void k3e(const float* __restrict__ S, const int* __restrict__ Meta,
                    unsigned char* __restrict__ Flags, int* __restrict__ CandI,
                    float* __restrict__ CandV, int* __restrict__ CandCnt) {
    int i = blockIdx.x * 256 + threadIdx.x;
    if (i >= NBASE) return;
    const float4* S4 = (const float4*)S;
    float4 sa = S4[(size_t)i*2], sb = S4[(size_t)i*2 + 1];
    float sv[8] = {sa.x, sa.y, sa.z, sa.w, sb.x, sb.y, sb.z, sb.w};
    unsigned long long flw = 0ull;
    #pragma unroll
    for (int e = 0; e < 8; ++e) {
        int B = Meta[e*4], B2 = Meta[e*4+2];
        int b = bin1(sv[e]);
        int fl = 0;
        if (b > B) fl = 1;
        else if (b == B) {
            int b2 = bin2(sv[e], B);
            if (b2 > B2) fl = 1;
            else if (b2 == B2) {
                int k = atomicAdd(&CandCnt[e], 1);
                if (k < CAP2) { CandI[e*CAP2 + k] = i; CandV[e*CAP2 + k] = sv[e]; }
            }
        }
        flw |= ((unsigned long long)fl) << (8*e);
    }
    *(unsigned long long*)(Flags + (size_t)i * 8) = flw;
}

// ---------- K3f: pick need2 winners in boundary sub-bin (value desc, idx asc) ----------
__global__ void k3f(const int* __restrict__ Meta, const int* __restrict__ CandCnt,
                    int* __restrict__ CandI, const float* __restrict__ CandV,
                    unsigned char* __restrict__ Flags) {
    int e = blockIdx.x;
    if (threadIdx.x != 0) return;
    int need2 = Meta[e*4+3];
    int n = min(CandCnt[e], CAP2);
    for (int t = 0; t < need2; ++t) {
        int best = -1, bi = 0; float bv = 0.f;
        for (int j = 0; j < n; ++j) {
            int ij = CandI[e*CAP2 + j];
            if (ij < 0) continue;
            float vj = CandV[e*CAP2 + j];
            if (best < 0 || vj > bv || (vj == bv && ij < bi)) { best = j; bv = vj; bi = ij; }
        }
        if (best < 0) break;
        Flags[(size_t)bi * NE + e] = 1;
        CandI[e*CAP2 + best] = -1;
    }
}

// ---------- K4: weighted accumulate of selected rows -> per-block partials ----------
__global__ void k4_part(const float* __restrict__ Bse, const float* __restrict__ S,
                        const float* __restrict__ InvN, const unsigned char* __restrict__ Flags,
                        float* __restrict__ Part) {
    int tid = threadIdx.x;
    float acc[NE][4];
    #pragma unroll
    for (int e = 0; e < NE; ++e)
        #pragma unroll
        for (int j = 0; j < 4; ++j) acc[e][j] = 0.f;
    for (int i = blockIdx.x; i < NBASE; i += gridDim.x) {
        unsigned long long fl = *(const unsigned long long*)(Flags + (size_t)i * 8);
        if (!fl) continue;
        float inv = InvN[i];
        const float4* S4 = (const float4*)S;
        float4 sa = S4[(size_t)i*2], sb = S4[(size_t)i*2 + 1];
        float sv[8] = {sa.x, sa.y, sa.z, sa.w, sb.x, sb.y, sb.z, sb.w};
        float coef[NE];
        #pragma unroll
        for (int e = 0; e < NE; ++e)
            coef[e] = ((fl >> (8*e)) & 0xffull) ? sqrtf(fmaxf(sv[e], 0.f)) * inv : 0.f;
        float4 b = ((const float4*)(Bse + (size_t)i * DIM))[tid];
        #pragma unroll
        for (int e = 0; e < NE; ++e) {
            acc[e][0] += coef[e] * b.x;
            acc[e][1] += coef[e] * b.y;
            acc[e][2] += coef[e] * b.z;
            acc[e][3] += coef[e] * b.w;
        }
    }
    float4* P4 = (float4*)Part;
    #pragma unroll
    for (int e = 0; e < NE; ++e)
        P4[(size_t)blockIdx.x*2048 + e*256 + tid] =
            make_float4(acc[e][0], acc[e][1], acc[e][2], acc[e][3]);
}

// fallback when ws is too small for partials
__global__ void k4_atomic(const float* __restrict__ Bse, const float* __restrict__ S,
                          const float* __restrict__ InvN, const unsigned char* __restrict__ Flags,
                          float* __restrict__ Acc) {
    int tid = threadIdx.x;
    float acc[NE][4];
    #pragma unroll
    for (int e = 0; e < NE; ++e)
        #pragma unroll
        for (int j = 0; j < 4; ++j) acc[e][j] = 0.f;
    for (int i = blockIdx.x; i < NBASE; i += gridDim.x) {
        unsigned long long fl = *(const unsigned long long*)(Flags + (size_t)i * 8);
        if (!fl) continue;
        float inv = InvN[i];
        const float4* S4 = (const float4*)S;
        float4 sa = S4[(size_t)i*2], sb = S4[(size_t)i*2 + 1];
        float sv[8] = {sa.x, sa.y, sa.z, sa.w, sb.x, sb.y, sb.z, sb.w};
        float coef[NE];
        #pragma unroll
        for (int e = 0; e < NE; ++e)
            coef[e] = ((fl >> (8*e)) & 0xffull) ? sqrtf(fmaxf(sv[e], 0.f)) * inv : 0.f;
        float4 b = ((const float4*)(Bse + (size_t)i * DIM))[tid];
        #pragma unroll
        for (int e = 0; e < NE; ++e) {
            acc[e][0] += coef[e] * b.x;
            acc[e][1] += coef[e] * b.y;
            acc[e][2] += coef[e] * b.z;
            acc[e][3] += coef[e] * b.w;
        }
    }
    #pragma unroll
    for (int e = 0; e < NE; ++e)
        #pragma unroll
        for (int j = 0; j < 4; ++j)
            atomicAdd(&Acc[e*DIM + tid*4 + j], acc[e][j]);
}

// ---------- K4b: reduce partials (16 slices per output chunk) ----------
__global__ void k4b(const float* __restrict__ Part, float* __restrict__ Acc, int nparts) {
    int g = blockIdx.x * 256 + threadIdx.x;   // 32768 threads
    int c = g & 2047, s = g >> 11;
    const float4* P4 = (const float4*)Part;
    float4 a = make_float4(0.f,0.f,0.f,0.f);
    for (int b = s; b < nparts; b += 16) a = add4(a, P4[(size_t)b*2048 + c]);
    atomicAdd(&Acc[c*4+0], a.x);
    atomicAdd(&Acc[c*4+1], a.y);
    atomicAdd(&Acc[c*4+2], a.z);
    atomicAdd(&Acc[c*4+3], a.w);
}

// ---------- K5: A = normalize(Acc) ----------
__global__ void k5(const float* __restrict__ Acc, float* __restrict__ A) {
    int e = blockIdx.x, tid = threadIdx.x;
    __shared__ float red[4];
    float4 a = ((const float4*)Acc)[e*256 + tid];
    float ss = block_sum(dot4(a,a), red);
    float inv = 1.f / fmaxf(sqrtf(ss), 1e-12f);
    ((float4*)A)[e*256 + tid] = scale4(a, inv);
}

// ---------- K6: out = normalize(fn - (fn.a) a), wave-per-row ----------
__global__ void k6(const float* __restrict__ F, const float* __restrict__ A,
                   float* __restrict__ Out) {
    int wv = threadIdx.x >> 6, lane = threadIdx.x & 63;
    size_t rid = (size_t)blockIdx.x * 4 + wv;
    int e = (int)(rid >> 10);
    const float4* f4 = (const float4*)(F + rid * DIM);
    const float4* a4 = (const float4*)(A + (size_t)e * DIM);
    float4 f0 = f4[lane], f1 = f4[64+lane], f2 = f4[128+lane], f3 = f4[192+lane];
    float4 a0 = a4[lane], a1 = a4[64+lane], a2 = a4[128+lane], a3 = a4[192+lane];
    float ss = dot4(f0,f0) + dot4(f1,f1) + dot4(f2,f2) + dot4(f3,f3);
    ss = wave_sum_xor(ss);
    float invf = 1.f / fmaxf(sqrtf(ss), 1e-12f);
    f0 = scale4(f0, invf); f1 = scale4(f1, invf); f2 = scale4(f2, invf); f3 = scale4(f3, invf);
    float c = dot4(f0,a0) + dot4(f1,a1) + dot4(f2,a2) + dot4(f3,a3);
    c = wave_sum_xor(c);
    float4 r0 = make_float4(f0.x - c*a0.x, f0.y - c*a0.y, f0.z - c*a0.z, f0.w - c*a0.w);
    float4 r1 = make_float4(f1.x - c*a1.x, f1.y - c*a1.y, f1.z - c*a1.z, f1.w - c*a1.w);
    float4 r2 = make_float4(f2.x - c*a2.x, f2.y - c*a2.y, f2.z - c*a2.z, f2.w - c*a2.w);
    float4 r3 = make_float4(f3.x - c*a3.x, f3.y - c*a3.y, f3.z - c*a3.z, f3.w - c*a3.w);
    float rs = dot4(r0,r0) + dot4(r1,r1) + dot4(r2,r2) + dot4(r3,r3);
    rs = wave_sum_xor(rs);
    float invr = 1.f / fmaxf(sqrtf(rs), 1e-12f);
    float4* o4 = (float4*)(Out + rid * DIM);
    o4[lane]     = scale4(r0, invr);
    o4[64+lane]  = scale4(r1, invr);
    o4[128+lane] = scale4(r2, invr);
    o4[192+lane] = scale4(r3, invr);
}

extern "C" void kernel_launch(void* const* d_in, const int* in_sizes, int n_in,
                              void* d_out, int out_size, void* d_ws, size_t ws_size,
                              hipStream_t stream) {
    const float* F   = (const float*)d_in[0];   // (8,1024,1024)
    const float* Bse = (const float*)d_in[1];   // (100000,1024)
    float* Out = (float*)d_out;

    char* ws = (char*)d_ws;
    size_t off = 0;
    auto alloc = [&](size_t bytes) -> void* {
        void* p = ws + off;
        off += (bytes + 255) & ~(size_t)255;
        return p;
    };
    float* Q     = (float*)alloc((size_t)NE * DIM * 4);
    float* Qpart = (float*)alloc((size_t)NE * 32 * DIM * 4);       // 1 MB
    float* S     = (float*)alloc((size_t)NBASE * NE * 4);          // 3.2 MB
    float* ST    = (float*)alloc((size_t)NE * NBASE * 4);          // 3.2 MB
    float* InvN  = (float*)alloc((size_t)NBASE * 4);               // 0.4 MB
    unsigned char* Flags = (unsigned char*)alloc((size_t)NBASE * NE); // 0.8 MB
    int*   Zero  = (int*)alloc((size_t)(NE*NB1 + NE*256 + NE) * 4);   // Hist+SubHist+CandCnt
    int*   Hist    = Zero;
    int*   SubHist = Zero + NE*NB1;
    int*   CandCnt = Zero + NE*NB1 + NE*256;
    int*   Meta  = (int*)alloc((size_t)NE * 4 * 4);
    int*   CandI = (int*)alloc((size_t)NE * CAP2 * 4);
    float* CandV = (float*)alloc((size_t)NE * CAP2 * 4);
    float* Acc   = (float*)alloc((size_t)NE * DIM * 4);
    float* A     = (float*)alloc((size_t)NE * DIM * 4);

    // Part buffer sized by remaining workspace
    int nparts = 0;
    float* Part = nullptr;
    size_t partBytes512 = (size_t)512 * NE * DIM * 4;   // 16 MB
    size_t partBytes256 = (size_t)256 * NE * DIM * 4;   //  8 MB
    if (ws_size >= off + partBytes512)      { nparts = 512; Part = (float*)alloc(partBytes512); }
    else if (ws_size >= off + partBytes256) { nparts = 256; Part = (float*)alloc(partBytes256); }

    hipMemsetAsync(Zero, 0, (size_t)(NE*NB1 + NE*256 + NE) * 4, stream);
    hipMemsetAsync(Acc, 0, (size_t)NE * DIM * 4, stream);

    k1a<<<NE*32, 256, 0, stream>>>(F, Qpart);
    k1b<<<NE, 256, 0, stream>>>(Qpart, Q);
    k2_sim<<<(NBASE+3)/4, 256, 0, stream>>>(Bse, Q, S, ST, InvN);
    k3a<<<NE*32, 256, 0, stream>>>(ST, Hist);
    k3b<<<NE, 256, 0, stream>>>(Hist, Meta);
    k3c<<<NE*32, 256, 0, stream>>>(ST, Meta, SubHist);
    k3d<<<NE, 64, 0, stream>>>(SubHist, Meta);
    k3e<<<(NBASE+255)/256, 256, 0, stream>>>(S, Meta, Flags, CandI, CandV, CandCnt);
    k3f<<<NE, 64, 0, stream>>>(Meta, CandCnt, CandI, CandV, Flags);
    if (nparts) {
        k4_part<<<nparts, 256, 0, stream>>>(Bse, S, InvN, Flags, Part);
        k4b<<<128, 256, 0, stream>>>(Part, Acc, nparts);
    } else {
        k4_atomic<<<512, 256, 0, stream>>>(Bse, S, InvN, Flags, Acc);
    }
    k5<<<NE, 256, 0, stream>>>(Acc, A);
    k6<<<(NE*1024)/4, 256, 0, stream>>>(F, A, Out);
}